// Round 10
// baseline (32.578 us; speedup 1.0000x reference)
//
#include <hip/hip_runtime.h>
#include <hip/hip_bf16.h>
#include <cstdint>

// LearnableUpsamplingLayer: polyphase decomposition + bf16 MFMA.
// B=8, T=16384, C=64, F=64, filter=5, leaky 0.3.
// out[b,2t+p,f] = sum_tap M_p[tap][c,f] * x[t-1+tap, c]   (x outside [0,T) = 0)
// Even p=0: 3 taps; odd p=1: 4 taps. Frames 0,1 get a precomputed correction
// (the polyphase substitution leaks a (1-w)*x[0] term through blend[-1]).
//
// R10: block-level 2-phase pipeline (T3 minimum recipe). Each block: 128
// time-pairs = 2 segments, double-buffered 80-row f32 LDS buffers (40 KB).
// Per segment: STAGE(next; 5 global_load_lds per wave, uniform) ->
// s_waitcnt vmcnt(5) (counted: next-seg loads remain in flight across the
// whole current compute) -> raw s_barrier + sched_barrier(0) -> 4 windows of
// ds_read + 14 MFMA + dwordx4 stores. 2 barriers per block, never vmcnt(0)
// except the last segment. Grid 1024 = 4 blocks/CU exactly (LDS-capped).
// XOR involution swizzle on global source chunk + LDS read offset (linear
// DMA dest, rule 21). Operand-swapped MFMA (W=A) -> each thread owns 4
// consecutive filters -> 2 global_store_dwordx4 per window.

#define T_ 16384
#define TWO_T 32768
#define BROWS 80           // rows per LDS buffer (frames ps-8 .. ps+71)

typedef __bf16 bf16x8 __attribute__((ext_vector_type(8)));
typedef float  f32x4  __attribute__((ext_vector_type(4)));
typedef unsigned short u16x8 __attribute__((ext_vector_type(8)));

__device__ __forceinline__ float sigmoidf_(float z) {
    return 1.0f / (1.0f + expf(-z));
}

__device__ __forceinline__ unsigned short f2bf(float f) {
    union { float f; uint32_t u; } v; v.f = f;
    uint32_t u = v.u;
    return (unsigned short)((u + 0x7FFFu + ((u >> 16) & 1u)) >> 16);
}

// ---------------- prep: 64 blocks x 64 threads (unchanged, proven).
// Blocks 0..55: the 7 polyphase matrices as packed bf16 fragments:
//   frag (phase, ks, nt): lane l elem i = M[tap=ks>>1][c=(ks&1)*32+(l>>4)*8+i]
//                                          [f=nt*16+(l&15)]
// Blocks 56..63: b = fi-56; corr[b][{E,O}][f] = sum_c K[{1,0}][c][f]*(1-w_c)*x[b,0,c]
// Block 63 additionally zeroes the 256B zero-pad (OOB redirect target).
__global__ void lu_prep_kernel(const float* __restrict__ iw,
                               const float* __restrict__ ck,
                               const float* __restrict__ x,
                               unsigned short* __restrict__ bp,
                               float* __restrict__ corrf,
                               float* __restrict__ zp) {
    int fi = blockIdx.x;
    int l  = threadIdx.x;
    if (fi < 56) {
        int phase, ks, nt;
        if (fi < 24) { phase = 0; ks = fi >> 2; nt = fi & 3; }
        else         { phase = 1; ks = (fi - 24) >> 2; nt = (fi - 24) & 3; }
        int tap = ks >> 1;
        int n   = nt * 16 + (l & 15);
        int c0  = ((ks & 1) << 5) + ((l >> 4) << 3);
        u16x8 pk;
#pragma unroll
        for (int i = 0; i < 8; ++i) {
            int c = c0 + i;
            float w = sigmoidf_(iw[c]);
            float v;
            #define CK(k) ck[((k) * 64 + c) * 64 + n]
            if (phase == 0) {
                if (tap == 0)      v = CK(0) + w * CK(1);
                else if (tap == 1) v = (1.f - w) * CK(1) + CK(2) + w * CK(3);
                else               v = (1.f - w) * CK(3) + CK(4);
            } else {
                if (tap == 0)      v = w * CK(0);
                else if (tap == 1) v = (1.f - w) * CK(0) + CK(1) + w * CK(2);
                else if (tap == 2) v = (1.f - w) * CK(2) + CK(3) + w * CK(4);
                else               v = (1.f - w) * CK(4);
            }
            #undef CK
            pk[i] = f2bf(v);
        }
        *(u16x8*)(bp + (((size_t)fi * 64) + l) * 8) = pk;
    } else {
        int b = fi - 56;
        int f = l;
        float cE = 0.f, cO = 0.f;
#pragma unroll
        for (int c = 0; c < 64; ++c) {
            float w = sigmoidf_(iw[c]);
            float g = (1.f - w) * x[(size_t)b * T_ * 64 + c];
            cE += ck[(64 + c) * 64 + f] * g;   // K1
            cO += ck[c * 64 + f] * g;          // K0
        }
        corrf[b * 128 + f]      = cE;
        corrf[b * 128 + 64 + f] = cO;
        if (fi == 63) zp[l] = 0.f;             // 64 floats = 256 B zero pad
    }
}

// ---------------- main ----------------
__device__ __forceinline__ void gload16(const float* g, float* l) {
    __builtin_amdgcn_global_load_lds(
        (const __attribute__((address_space(1))) uint32_t*)g,
        (__attribute__((address_space(3))) uint32_t*)l, 16, 0, 0);
}

__device__ __forceinline__ bf16x8 pack8(f32x4 a, f32x4 b) {
    bf16x8 r;
    r[0] = (__bf16)a[0]; r[1] = (__bf16)a[1];
    r[2] = (__bf16)a[2]; r[3] = (__bf16)a[3];
    r[4] = (__bf16)b[0]; r[5] = (__bf16)b[1];
    r[6] = (__bf16)b[2]; r[7] = (__bf16)b[3];
    return r;
}

__global__ __launch_bounds__(256, 4) void lu_main_kernel(
        const float* __restrict__ x,
        const unsigned short* __restrict__ bp,
        const float* __restrict__ corrf,
        const float* __restrict__ bias,
        const float* __restrict__ zp,
        float* __restrict__ out) {
    __shared__ __align__(16) float xl[2 * BROWS * 64];   // 40,960 B

    const int bid  = blockIdx.x;        // 0..1023
    const int b    = bid >> 7;          // batch
    const int q    = bid & 127;
    const int p0   = q << 7;            // 128 time-pairs per block
    const int lane = threadIdx.x & 63;
    const int wv   = threadIdx.x >> 6;  // wave = filter tile

    const float* xb = x + (size_t)b * T_ * 64;

    // ---- weight A-fragments + bias (oldest VMEM; done by first wait) ----
    bf16x8 We[6], Wo[8];
#pragma unroll
    for (int ks = 0; ks < 6; ++ks)
        We[ks] = __builtin_bit_cast(bf16x8,
            *(const u16x8*)(bp + (((size_t)(ks * 4 + wv)) * 64 + lane) * 8));
#pragma unroll
    for (int ks = 0; ks < 8; ++ks)
        Wo[ks] = __builtin_bit_cast(bf16x8,
            *(const u16x8*)(bp + (((size_t)(24 + ks * 4 + wv)) * 64 + lane) * 8));

    const int hi   = lane >> 4;
    const int hi2  = hi << 1;
    const int col  = lane & 15;         // time-pair within window
    const float4 bias4 = *(const float4*)(bias + (wv << 4) + (hi << 2));

    // STAGE(buf, ps): buffer rows j=0..79 <- frames ps-8 .. ps+71.
    // Wave wv stages groups k=0..4: rows j0=4wv+16k (wave-uniform dest);
    // lane: row j=j0+(lane>>4), chunk slot s=lane&15, global chunk s^(j&7)
    // (XOR involution; reads undo it). OOB frames -> zero pad.
    #define STAGE(buf, ps)                                                  \
    {                                                                       \
        _Pragma("unroll")                                                   \
        for (int k = 0; k < 5; ++k) {                                       \
            int j0 = (wv << 2) + (k << 4);                                  \
            int j  = j0 + (lane >> 4);                                      \
            int t  = (ps) - 8 + j;                                          \
            int ch = (lane & 15) ^ (j & 7);                                 \
            const float* gp = ((unsigned)t < (unsigned)T_)                  \
                            ? xb + ((size_t)t << 6) + (ch << 2)             \
                            : zp + (ch << 2);                               \
            gload16(gp, xl + (((buf) * BROWS) + j0) * 64);                  \
        }                                                                   \
    }

    // ---- prologue: stage segment 0 into buffer 0 ----
    STAGE(0, p0)

#pragma unroll
    for (int s = 0; s < 2; ++s) {
        const int ps = p0 + (s << 6);

        // issue next segment's loads first (in flight across this compute)
        if (s == 0) {
            STAGE(1, p0 + 64)
            asm volatile("s_waitcnt vmcnt(5)" ::: "memory");
        } else {
            asm volatile("s_waitcnt vmcnt(0)" ::: "memory");
        }
        __builtin_amdgcn_s_barrier();
        __builtin_amdgcn_sched_barrier(0);

        const char* xwb = (const char*)(xl + s * (BROWS * 64));

#pragma unroll
        for (int w = 0; w < 4; ++w) {
            f32x4 accE = {0.f, 0.f, 0.f, 0.f};
            f32x4 accO = {0.f, 0.f, 0.f, 0.f};
#pragma unroll
            for (int tap = 0; tap < 4; ++tap) {
                int j    = (w << 4) + col + tap + 7;     // row 7..74
                int key  = j & 7;
                int off0 = (j << 8) + ((hi2 ^ key) << 4);
                f32x4 qa = *(const f32x4*)(xwb + off0);
                f32x4 qb = *(const f32x4*)(xwb + (off0 ^ 16));
                f32x4 qc = *(const f32x4*)(xwb + off0 + 128);
                f32x4 qd = *(const f32x4*)(xwb + ((off0 + 128) ^ 16));
                bf16x8 x0 = pack8(qa, qb);              // channels 0-31
                bf16x8 x1 = pack8(qc, qd);              // channels 32-63
                if (tap < 3) {
                    accE = __builtin_amdgcn_mfma_f32_16x16x32_bf16(We[tap * 2],     x0, accE, 0, 0, 0);
                    accE = __builtin_amdgcn_mfma_f32_16x16x32_bf16(We[tap * 2 + 1], x1, accE, 0, 0, 0);
                }
                accO = __builtin_amdgcn_mfma_f32_16x16x32_bf16(Wo[tap * 2],     x0, accO, 0, 0, 0);
                accO = __builtin_amdgcn_mfma_f32_16x16x32_bf16(Wo[tap * 2 + 1], x1, accO, 0, 0, 0);
            }

            // ---- boundary correction (output frames 0,1 of each batch) ----
            if (((q | s | w) == 0) && col == 0) {
                const float4 cE4 = *(const float4*)(corrf + b * 128 + (wv << 4) + (hi << 2));
                const float4 cO4 = *(const float4*)(corrf + b * 128 + 64 + (wv << 4) + (hi << 2));
                accE[0] -= cE4.x; accE[1] -= cE4.y; accE[2] -= cE4.z; accE[3] -= cE4.w;
                accO[0] -= cO4.x; accO[1] -= cO4.y; accO[2] -= cO4.z; accO[3] -= cO4.w;
            }

            // ---- epilogue: bias + leaky_relu, one dwordx4 store per phase ----
            const int tl = ps + (w << 4) + col;
            const size_t fbase = ((size_t)b * TWO_T + ((size_t)tl << 1)) * 64
                               + (wv << 4) + (hi << 2);
            float4 vE, vO;
            {
                float e0 = accE[0] + bias4.x, e1 = accE[1] + bias4.y,
                      e2 = accE[2] + bias4.z, e3 = accE[3] + bias4.w;
                vE.x = e0 >= 0.f ? e0 : 0.3f * e0;
                vE.y = e1 >= 0.f ? e1 : 0.3f * e1;
                vE.z = e2 >= 0.f ? e2 : 0.3f * e2;
                vE.w = e3 >= 0.f ? e3 : 0.3f * e3;
                float o0 = accO[0] + bias4.x, o1 = accO[1] + bias4.y,
                      o2 = accO[2] + bias4.z, o3 = accO[3] + bias4.w;
                vO.x = o0 >= 0.f ? o0 : 0.3f * o0;
                vO.y = o1 >= 0.f ? o1 : 0.3f * o1;
                vO.z = o2 >= 0.f ? o2 : 0.3f * o2;
                vO.w = o3 >= 0.f ? o3 : 0.3f * o3;
            }
            *(float4*)(out + fbase)      = vE;   // even frame 2*tl
            *(float4*)(out + fbase + 64) = vO;   // odd frame 2*tl+1
        }
    }
    #undef STAGE
}

extern "C" void kernel_launch(void* const* d_in, const int* in_sizes, int n_in,
                              void* d_out, int out_size, void* d_ws, size_t ws_size,
                              hipStream_t stream) {
    (void)in_sizes; (void)n_in; (void)out_size; (void)ws_size;
    const float* x    = (const float*)d_in[0];
    const float* iw   = (const float*)d_in[1];
    const float* ck   = (const float*)d_in[2];
    const float* bias = (const float*)d_in[3];
    float* out = (float*)d_out;
    unsigned short* bp = (unsigned short*)d_ws;            // 57,344 B
    float* corrf = (float*)((char*)d_ws + 57344);          // 4,096 B
    float* zp    = (float*)((char*)d_ws + 61440);          //   256 B zeros

    lu_prep_kernel<<<64, 64, 0, stream>>>(iw, ck, x, bp, corrf, zp);
    lu_main_kernel<<<1024, 256, 0, stream>>>(x, bp, corrf, bias, zp, out);
}